// Round 27
// baseline (4858.395 us; speedup 1.0000x reference)
//
// R27: GROWS 16->8 (6400 blocks; deeper queue, better stall hiding).
// Everything else identical to PASSING R26. Bit-identical f32 grid.
#include <hip/hip_runtime.h>
#include <math.h>

#define B 8
#define D 256
#define V 50257
#define VP 50304
#define BEAM 32
#define STEPS 16
#define MAXLEN 17
#define FNEG_INF (-3.4e38f)
#define NG 1571           // ceil(V/32)
#define NSG 50            // ceil(NG/32)
#define NSEG 197          // ceil(V/256)
#define VSEGP 200         // vsegs padded to multiple of NXCD
#define NXCD 8
#define GROWS 8           // rows per k_gemm block (occupancy lever)
#define NLCAP 800
#define SLOTCAP 1600
#define NSPLIT 25128      // root split of numpy pairwise tree for n=V
#define CHUNK 16384       // k_top LDS chunk (elements)

static_assert((V + 255) / 256 == NSEG, "NSEG mismatch");

// ===== compile-time replica of numpy pairwise_sum recursion tree =====
struct SchedT {
    int nl, nops, nlev, root, minLeaf;
    int lvlStart[36];
    int leafOff[NLCAP];
    int leafN[NLCAP];
    int sA[NLCAP];
    int sB[NLCAP];
    int sD[NLCAP];
};

constexpr SchedT build_sched(int off0, int n0) {
    SchedT s{};
    int sOff[64] = {}, sN[64] = {}, sPh[64] = {};
    int vSlot[64] = {}, vLev[64] = {};
    int oA[NLCAP] = {}, oB[NLCAP] = {}, oD[NLCAP] = {}, oL[NLCAP] = {};
    int sp = 0, vp = 0, nl = 0, nops = 0;
    s.minLeaf = 1 << 30;
    sOff[0] = off0; sN[0] = n0; sPh[0] = 0; sp = 1;
    while (sp) {
        int i = sp - 1;
        int n = sN[i];
        if (n <= 128) {                        // leaf (np_pairwise base case)
            s.leafOff[nl] = sOff[i]; s.leafN[nl] = n;
            if (n < s.minLeaf) s.minLeaf = n;
            vSlot[vp] = nl; vLev[vp] = 0; ++vp; ++nl; --sp; continue;
        }
        int n2 = (n / 2) - ((n / 2) % 8);
        int ph = sPh[i];
        if (ph == 0)      { sPh[i] = 1; sOff[sp] = sOff[i];      sN[sp] = n2;     sPh[sp] = 0; ++sp; }
        else if (ph == 1) { sPh[i] = 2; sOff[sp] = sOff[i] + n2; sN[sp] = n - n2; sPh[sp] = 0; ++sp; }
        else {
            int bI = --vp; int aI = --vp;      // a = left child, b = right child
            int lev = (vLev[aI] > vLev[bI] ? vLev[aI] : vLev[bI]) + 1;
            oA[nops] = vSlot[aI]; oB[nops] = vSlot[bI]; oD[nops] = NLCAP + nops; oL[nops] = lev;
            vSlot[vp] = NLCAP + nops; vLev[vp] = lev; ++vp; ++nops; --sp;
        }
    }
    s.nl = nl; s.nops = nops; s.root = vSlot[0];
    int maxl = 0;
    for (int k = 0; k < nops; ++k) if (oL[k] > maxl) maxl = oL[k];
    s.nlev = maxl;
    int cnt[36] = {};
    for (int k = 0; k < nops; ++k) cnt[oL[k]]++;
    int run = 0;
    s.lvlStart[0] = 0;
    for (int k = 1; k <= maxl; ++k) { s.lvlStart[k] = run; run += cnt[k]; cnt[k] = s.lvlStart[k]; }
    s.lvlStart[maxl + 1] = run;
    for (int k = 0; k < nops; ++k) { int p = cnt[oL[k]]++; s.sA[p] = oA[k]; s.sB[p] = oB[k]; s.sD[p] = oD[k]; }
    return s;
}

constexpr SchedT SCHL = build_sched(0, NSPLIT);
constexpr SchedT SCHR = build_sched(NSPLIT, V - NSPLIT);
static_assert(SCHL.nl <= NLCAP && SCHR.nl <= NLCAP, "leaf overflow");
static_assert(SCHL.nops <= NLCAP && SCHR.nops <= NLCAP, "op overflow");
static_assert(SCHL.nlev <= 34 && SCHR.nlev <= 34, "level overflow");
static_assert(SCHL.minLeaf >= 8 && SCHR.minLeaf >= 8, "leaf < 8 breaks 8-lane cluster");

// -------- init --------
__global__ void k_init(const int* __restrict__ initial_ids, const float* __restrict__ state,
                       float* __restrict__ cache, int* __restrict__ ids, float* __restrict__ scores) {
    int b = blockIdx.x, t = threadIdx.x;
    cache[b * D + t] = state[b * D + t];
    if (t == 0) { ids[b * MAXLEN] = initial_ids[b]; scores[b] = 0.f; }
}

// -------- x = tanh(seqdot(cache,U) + emb[last]); writes x AND xT --------
__global__ __launch_bounds__(256) void k_embed(const float* __restrict__ cache, const int* __restrict__ ids,
                                               const float* __restrict__ emb, const float* __restrict__ U,
                                               float* __restrict__ x, float* __restrict__ xT, int step) {
    int rr = blockIdx.x, j = threadIdx.x;
    __shared__ float sc[D];
    sc[j] = cache[rr * D + j];
    __syncthreads();
    int last = ids[rr * MAXLEN + step];
    float acc = 0.f;
    for (int d = 0; d < D; ++d)
        acc = __fadd_rn(acc, __fmul_rn(sc[d], U[d * D + j]));   // sequential f32, no FMA
    float pre = __fadd_rn(acc, emb[(size_t)last * D + j]);
    float xv = (float)tanh((double)pre);
    x[rr * D + j] = xv;
    xT[(size_t)j * 256 + rr] = xv;                              // fused transpose write
}

// -------- logits GEMM (scalar, 8 rows/block, XCD-swizzled) + segment max --------
__global__ __launch_bounds__(256) void k_gemm(const float* __restrict__ xT, const float* __restrict__ W,
                                              float* __restrict__ L, float* __restrict__ segMax,
                                              int rows, int rowBlocks) {
    int t = threadIdx.x;
    int xcd = blockIdx.x % NXCD;
    int slot = blockIdx.x / NXCD;
    int vidx = slot / rowBlocks;
    int rg = slot % rowBlocks;
    int vseg = xcd + NXCD * vidx;
    if (vseg >= NSEG) return;
    int v = vseg * 256 + t;
    int r0 = rg * GROWS;
    bool vok = (v < V);
    float acc[GROWS];
#pragma unroll
    for (int r = 0; r < GROWS; ++r) acc[r] = 0.f;
    for (int d = 0; d < D; ++d) {
        float w = vok ? W[(size_t)d * V + v] : 0.f;  // coalesced vector load
        const float* xp = xT + (size_t)d * 256 + r0; // block-uniform -> s_load
#pragma unroll
        for (int r = 0; r < GROWS; ++r)
            acc[r] = __fadd_rn(acc[r], __fmul_rn(xp[r], w));   // same per-(r,v) order as R10-R26
    }
#pragma unroll
    for (int r = 0; r < GROWS; ++r)
        if (vok && r0 + r < rows) L[(size_t)(r0 + r) * VP + v] = acc[r];

    // segment max per row (fmax reduce: order-independent, exact)
    __shared__ float wmax[4][GROWS];
    int wave = t >> 6, lane = t & 63;
#pragma unroll
    for (int r = 0; r < GROWS; ++r) {
        float mv = vok ? acc[r] : FNEG_INF;
#pragma unroll
        for (int o = 1; o < 64; o <<= 1) mv = fmaxf(mv, __shfl_xor(mv, o));
        if (lane == 0) wmax[wave][r] = mv;
    }
    __syncthreads();
    if (t < GROWS && r0 + t < rows) {
        float mv = fmaxf(fmaxf(wmax[0][t], wmax[1][t]), fmaxf(wmax[2][t], wmax[3][t]));
        segMax[(size_t)(r0 + t) * NSEG + vseg] = mv;
    }
}

// -------- exact numpy-pairwise base-case element: f32(exp(f64(L-m))) --------
__device__ __forceinline__ float Ev(const float* __restrict__ a, float m, int i) {
    return (float)exp((double)__fsub_rn(a[i], m));
}

// -------- half-tree exp-sum: blockIdx.y = 0 (left) / 1 (right) --------
__global__ __launch_bounds__(1024) void k_lsf(const float* __restrict__ L, const float* __restrict__ segMax,
                                              float* __restrict__ pSum) {
    int rr = blockIdx.x, half = blockIdx.y, t = threadIdx.x;
    const float* Lr = L + (size_t)rr * VP;
    __shared__ float mS;
    __shared__ float vals[SLOTCAP];

    if (t < 64) {
        float mv = FNEG_INF;
        for (int s = t; s < NSEG; s += 64) mv = fmaxf(mv, segMax[(size_t)rr * NSEG + s]);
#pragma unroll
        for (int o = 1; o < 64; o <<= 1) mv = fmaxf(mv, __shfl_xor(mv, o));
        if (t == 0) mS = mv;
    }
    __syncthreads();
    float m = mS;

    const int* leafOff = half ? SCHR.leafOff : SCHL.leafOff;
    const int* leafN   = half ? SCHR.leafN   : SCHL.leafN;
    const int* sA      = half ? SCHR.sA      : SCHL.sA;
    const int* sB      = half ? SCHR.sB      : SCHL.sB;
    const int* sD      = half ? SCHR.sD      : SCHL.sD;
    const int* lvlStart= half ? SCHR.lvlStart: SCHL.lvlStart;
    int nl   = half ? SCHR.nl   : SCHL.nl;
    int nlev = half ? SCHR.nlev : SCHL.nlev;
    int root = half ? SCHR.root : SCHL.root;

    // leaf sums: 8-lane clusters, numpy accumulator j = lane
    int cl = t >> 3, j = t & 7;
    for (int l = cl; l < nl; l += 128) {
        int off = leafOff[l], n = leafN[l];
        int n8 = n - (n % 8);
        float r = Ev(Lr, m, off + j);
        for (int i = 8; i < n8; i += 8) r = __fadd_rn(r, Ev(Lr, m, off + i + j));
        float s1 = __fadd_rn(r,  __shfl_xor(r, 1));     // commutative: bitwise == numpy tree
        float s2 = __fadd_rn(s1, __shfl_xor(s1, 2));
        float s3 = __fadd_rn(s2, __shfl_xor(s2, 4));
        if (j == 0) {
            float res = s3;
            for (int i = n8; i < n; ++i) res = __fadd_rn(res, Ev(Lr, m, off + i));
            vals[l] = res;
        }
    }
    __syncthreads();
    for (int lev = 1; lev <= nlev; ++lev) {
        for (int i = lvlStart[lev] + t; i < lvlStart[lev + 1]; i += 1024)
            vals[sD[i]] = __fadd_rn(vals[sA[i]], vals[sB[i]]);
        __syncthreads();
    }
    if (t == 0) pSum[rr * 2 + half] = vals[root];
}

// -------- k_top: m + lsf finalize + LDS-chunk group top-2 + extraction --------
__global__ __launch_bounds__(1024) void k_top(const float* __restrict__ L, const float* __restrict__ segMax,
                                              const float* __restrict__ pSum, const float* __restrict__ scores,
                                              float* __restrict__ candV, int* __restrict__ candI) {
    int rr = blockIdx.x, t = threadIdx.x;
    const float* Lr = L + (size_t)rr * VP;
    __shared__ float mS;
    __shared__ float buf[CHUNK];
    __shared__ float gval[NG]; __shared__ int gidx[NG]; __shared__ unsigned gmask[NG];
    __shared__ float gv2[NG]; __shared__ int gi2[NG];
    __shared__ float sgval[64]; __shared__ int sgtok[64]; __shared__ int sggrp[64];

    if (t < 64) {
        float mv = FNEG_INF;
        for (int s = t; s < NSEG; s += 64) mv = fmaxf(mv, segMax[(size_t)rr * NSEG + s]);
#pragma unroll
        for (int o = 1; o < 64; o <<= 1) mv = fmaxf(mv, __shfl_xor(mv, o));
        if (t == 0) mS = mv;
    }
    __syncthreads();
    float m = mS;
    float lsf = (float)log((double)__fadd_rn(pSum[rr * 2 + 0], pSum[rr * 2 + 1]));  // root combine
    float sc = scores[rr];

    // ---- group top-2 via LDS chunks, rotated per-thread scan (no shuffles) ----
    for (int c = 0; c < (V + CHUNK - 1) / CHUNK; ++c) {
        int base = c * CHUNK;
        int cnt = V - base; if (cnt > CHUNK) cnt = CHUNK;
        int cnt4 = (cnt + 3) >> 2;                       // pad reads stay < VP
        const float4* L4 = (const float4*)(Lr + base);
        float4* B4 = (float4*)buf;
        for (int i = t; i < cnt4; i += 1024) B4[i] = L4[i];
        __syncthreads();
        int gBase = base >> 5;
        int gCnt = (cnt + 31) >> 5;
        for (int g = gBase + t; g < gBase + gCnt; g += 1024) {
            int local = (g - gBase) * 32;
            float b1v = FNEG_INF, b2v = FNEG_INF; int b1i = 0x7fffffff, b2i = 0x7fffffff;
            for (int k = 0; k < 32; ++k) {
                int kk = (k + t) & 31;                   // rotation: conflict-free
                int col = g * 32 + kk;
                if (col >= V) continue;
                float val = __fadd_rn(sc, __fsub_rn(__fsub_rn(buf[local + kk], m), lsf));
                if (val > b1v || (val == b1v && col < b1i)) {
                    b2v = b1v; b2i = b1i; b1v = val; b1i = col;
                } else if (val > b2v || (val == b2v && col < b2i)) {
                    b2v = val; b2i = col;
                }
            }
            gval[g] = b1v; gidx[g] = b1i; gv2[g] = b2v; gi2[g] = b2i; gmask[g] = 0u;
        }
        __syncthreads();
    }

    // ---- supergroup table ----
    int wv = t >> 6, ln = t & 63;
    for (int s2 = wv * 2; s2 < NSG; s2 += 32) {
        int s = s2 + (ln >> 5);
        int g = s2 * 32 + ln;
        bool lives = (s < NSG);
        bool live = lives && (g < NG);
        float val = live ? gval[g] : FNEG_INF;
        int tok = live ? gidx[g] : 0x7fffffff;
        int grp = live ? g : -1;
#pragma unroll
        for (int o = 1; o < 32; o <<= 1) {
            float v2 = __shfl_xor(val, o);
            int t2 = __shfl_xor(tok, o);
            int g3 = __shfl_xor(grp, o);
            if (v2 > val || (v2 == val && t2 < tok)) { val = v2; tok = t2; grp = g3; }
        }
        if (lives && (ln & 31) == 0) { sgval[s] = val; sgtok[s] = tok; sggrp[s] = grp; }
    }
    __syncthreads();
    if (t >= 64) return;                                  // rounds run on wave 0 only

    // ---- 32 extraction rounds (pure LDS; global rescan only on repeat hits) ----
    for (int it = 0; it < 32; ++it) {
        float val = (t < NSG) ? sgval[t] : FNEG_INF;
        int tok = (t < NSG) ? sgtok[t] : 0x7fffffff;
        int grp = (t < NSG) ? sggrp[t] : -1;
#pragma unroll
        for (int o = 1; o < 64; o <<= 1) {                // butterfly all-reduce
            float v2 = __shfl_xor(val, o);
            int t2 = __shfl_xor(tok, o);
            int g3 = __shfl_xor(grp, o);
            if (v2 > val || (v2 == val && t2 < tok)) { val = v2; tok = t2; grp = g3; }
        }
        int gw = grp, tw = tok;                           // all lanes hold winner
        unsigned oldmask = gmask[gw];                     // read before write (program order)
        unsigned newmask = oldmask | (1u << (tw & 31));
        if (t == 0) {
            candV[rr * 32 + it] = val;
            candI[rr * 32 + it] = tw;
            gmask[gw] = newmask;
        }
        if (__popc(oldmask) == 0) {                       // first hit: promote stored 2nd
            if (t == 0) { gval[gw] = gv2[gw]; gidx[gw] = gi2[gw]; }
        } else {                                          // repeat hit: masked global rescan
            int col = gw * 32 + (t & 31);
            bool live = (col < V) && !((newmask >> (t & 31)) & 1u);
            float nv = live ? __fadd_rn(sc, __fsub_rn(__fsub_rn(Lr[col], m), lsf)) : FNEG_INF;
            int nix = live ? col : 0x7fffffff;
#pragma unroll
            for (int o = 1; o < 32; o <<= 1) {
                float v2 = __shfl_xor(nv, o);
                int i2 = __shfl_xor(nix, o);
                if (v2 > nv || (v2 == nv && i2 < nix)) { nv = v2; nix = i2; }
            }
            if (t == 0) { gval[gw] = nv; gidx[gw] = nix; }
        }
        // rebuild supergroup of gw
        int s = gw >> 5;
        int gg = s * 32 + (t & 31);
        bool lv = (gg < NG);
        float sv = lv ? gval[gg] : FNEG_INF;
        int st = lv ? gidx[gg] : 0x7fffffff;
        int sg2 = lv ? gg : -1;
#pragma unroll
        for (int o = 1; o < 32; o <<= 1) {
            float v2 = __shfl_xor(sv, o);
            int t2 = __shfl_xor(st, o);
            int g3 = __shfl_xor(sg2, o);
            if (v2 > sv || (v2 == sv && t2 < st)) { sv = v2; st = t2; sg2 = g3; }
        }
        if (t == 0) { sgval[s] = sv; sgtok[s] = st; sggrp[s] = sg2; }
    }
}

// -------- PARALLEL per-batch merge (unchanged from R15) --------
__global__ __launch_bounds__(256) void k_merge(const float* __restrict__ candV, const int* __restrict__ candI,
                                               float* __restrict__ scoresNxt,
                                               const int* __restrict__ idsCur, int* __restrict__ idsNxt,
                                               const float* __restrict__ x, float* __restrict__ cacheNxt,
                                               int beam0, int step) {
    int b = blockIdx.x, t = threadIdx.x;
    int n = beam0 * BEAM;
    __shared__ float mval[BEAM * BEAM]; __shared__ int mbeam[BEAM * BEAM]; __shared__ int mtok[BEAM * BEAM];
    __shared__ float rv[256]; __shared__ int rk[256]; __shared__ int rs[256];
    __shared__ float wval[BEAM]; __shared__ int wbeam[BEAM]; __shared__ int wtok[BEAM];

    for (int i = t; i < n; i += 256) {
        int beam = i >> 5;
        int rr = b * beam0 + beam;
        mval[i] = candV[rr * BEAM + (i & 31)];
        mbeam[i] = beam;
        mtok[i] = candI[rr * BEAM + (i & 31)];
    }
    __syncthreads();

    for (int it = 0; it < BEAM; ++it) {
        float bv = FNEG_INF; int bk = 0x7fffffff; int bs = -1;
        for (int i = t; i < n; i += 256) {
            float v = mval[i];
            int gi = mbeam[i] * V + mtok[i];
            if (v > bv || (v == bv && gi < bk)) { bv = v; bk = gi; bs = i; }
        }
        rv[t] = bv; rk[t] = bk; rs[t] = bs; __syncthreads();
        for (int o = 128; o > 0; o >>= 1) {
            if (t < o) {
                if (rv[t + o] > rv[t] || (rv[t + o] == rv[t] && rk[t + o] < rk[t])) {
                    rv[t] = rv[t + o]; rk[t] = rk[t + o]; rs[t] = rs[t + o];
                }
            }
            __syncthreads();
        }
        if (t == 0) {
            int w = rs[0];
            wval[it] = rv[0]; wbeam[it] = mbeam[w]; wtok[it] = mtok[w];
            mval[w] = FNEG_INF;                      // consume winner
        }
        __syncthreads();
    }

    if (t < BEAM) {
        scoresNxt[b * BEAM + t] = wval[t];
        int src = b * beam0 + wbeam[t];
        for (int u = 0; u <= step; ++u)
            idsNxt[(b * BEAM + t) * MAXLEN + u] = idsCur[src * MAXLEN + u];
        idsNxt[(b * BEAM + t) * MAXLEN + step + 1] = wtok[t];
    }
    __syncthreads();
    for (int j = 0; j < BEAM; ++j) {
        int src = b * beam0 + wbeam[j];
        cacheNxt[(size_t)(b * BEAM + j) * D + t] = x[(size_t)src * D + t];
    }
}

// -------- output as float32 --------
__global__ void k_out(const int* __restrict__ ids, const float* __restrict__ scores, float* __restrict__ out) {
    int t = blockIdx.x * 256 + threadIdx.x;
    const int NI = B * BEAM * MAXLEN;
    if (t < NI) out[t] = (float)ids[t];
    else if (t < NI + B * BEAM) out[t] = scores[t - NI];
}

extern "C" void kernel_launch(void* const* d_in, const int* in_sizes, int n_in,
                              void* d_out, int out_size, void* d_ws, size_t ws_size,
                              hipStream_t stream) {
    const int* initial_ids = (const int*)d_in[0];
    const float* state = (const float*)d_in[1];
    const float* emb = (const float*)d_in[2];
    const float* W = (const float*)d_in[3];
    const float* U = (const float*)d_in[4];

    char* ws = (char*)d_ws;
    size_t off = 0;
    float* L = (float*)(ws + off);       off += (size_t)256 * VP * 4;
    float* x = (float*)(ws + off);       off += 256 * D * 4;
    float* xT = (float*)(ws + off);      off += 256 * D * 4;
    float* cacheA = (float*)(ws + off);  off += 256 * D * 4;
    float* cacheB = (float*)(ws + off);  off += 256 * D * 4;
    float* scoresA = (float*)(ws + off); off += 256 * 4;
    float* scoresB = (float*)(ws + off); off += 256 * 4;
    int* idsA = (int*)(ws + off);        off += 256 * MAXLEN * 4;
    int* idsB = (int*)(ws + off);        off += 256 * MAXLEN * 4;
    float* candV = (float*)(ws + off);   off += 256 * 32 * 4;
    int* candI = (int*)(ws + off);       off += 256 * 32 * 4;
    float* segMax = (float*)(ws + off);  off += (size_t)256 * NSEG * 4;
    float* pSum = (float*)(ws + off);    off += 256 * 2 * 4;

    if (ws_size < off) return;

    k_init<<<B, 256, 0, stream>>>(initial_ids, state, cacheA, idsA, scoresA);

    float* cCur = cacheA; float* cNxt = cacheB;
    float* sCur = scoresA; float* sNxt = scoresB;
    int* iCur = idsA; int* iNxt = idsB;

    for (int step = 0; step < STEPS; ++step) {
        int beam0 = (step == 0) ? 1 : BEAM;
        int rows = B * beam0;

        k_embed<<<rows, 256, 0, stream>>>(cCur, iCur, emb, U, x, xT, step);

        int rowBlocks = (rows + GROWS - 1) / GROWS;
        k_gemm<<<VSEGP * rowBlocks, 256, 0, stream>>>(xT, W, L, segMax, rows, rowBlocks);

        dim3 gl(rows, 2);
        k_lsf<<<gl, 1024, 0, stream>>>(L, segMax, pSum);
        k_top<<<rows, 1024, 0, stream>>>(L, segMax, pSum, sCur, candV, candI);
        k_merge<<<B, 256, 0, stream>>>(candV, candI, sNxt, iCur, iNxt, x, cNxt, beam0, step);

        float* tf; int* ti;
        tf = cCur; cCur = cNxt; cNxt = tf;
        tf = sCur; sCur = sNxt; sNxt = tf;
        ti = iCur; iCur = iNxt; iNxt = ti;
    }

    k_out<<<(B * BEAM * MAXLEN + B * BEAM + 255) / 256, 256, 0, stream>>>(iCur, sCur, (float*)d_out);
}

// Round 28
// 4160.083 us; speedup vs baseline: 1.1679x; 1.1679x over previous
//
// R28 = R26 restored (measured best: 4.166 ms). GROWS=16, XCD swizzle,
// fused embed->xT, split k_lsf/k_top, parallel merge. Bit-identical f32 grid.
#include <hip/hip_runtime.h>
#include <math.h>

#define B 8
#define D 256
#define V 50257
#define VP 50304
#define BEAM 32
#define STEPS 16
#define MAXLEN 17
#define FNEG_INF (-3.4e38f)
#define NG 1571           // ceil(V/32)
#define NSG 50            // ceil(NG/32)
#define NSEG 197          // ceil(V/256)
#define VSEGP 200         // vsegs padded to multiple of NXCD
#define NXCD 8
#define GROWS 16          // rows per k_gemm block (measured optimum)
#define NLCAP 800
#define SLOTCAP 1600
#define NSPLIT 25128      // root split of numpy pairwise tree for n=V
#define CHUNK 16384       // k_top LDS chunk (elements)

static_assert((V + 255) / 256 == NSEG, "NSEG mismatch");

// ===== compile-time replica of numpy pairwise_sum recursion tree =====
struct SchedT {
    int nl, nops, nlev, root, minLeaf;
    int lvlStart[36];
    int leafOff[NLCAP];
    int leafN[NLCAP];
    int sA[NLCAP];
    int sB[NLCAP];
    int sD[NLCAP];
};

constexpr SchedT build_sched(int off0, int n0) {
    SchedT s{};
    int sOff[64] = {}, sN[64] = {}, sPh[64] = {};
    int vSlot[64] = {}, vLev[64] = {};
    int oA[NLCAP] = {}, oB[NLCAP] = {}, oD[NLCAP] = {}, oL[NLCAP] = {};
    int sp = 0, vp = 0, nl = 0, nops = 0;
    s.minLeaf = 1 << 30;
    sOff[0] = off0; sN[0] = n0; sPh[0] = 0; sp = 1;
    while (sp) {
        int i = sp - 1;
        int n = sN[i];
        if (n <= 128) {                        // leaf (np_pairwise base case)
            s.leafOff[nl] = sOff[i]; s.leafN[nl] = n;
            if (n < s.minLeaf) s.minLeaf = n;
            vSlot[vp] = nl; vLev[vp] = 0; ++vp; ++nl; --sp; continue;
        }
        int n2 = (n / 2) - ((n / 2) % 8);
        int ph = sPh[i];
        if (ph == 0)      { sPh[i] = 1; sOff[sp] = sOff[i];      sN[sp] = n2;     sPh[sp] = 0; ++sp; }
        else if (ph == 1) { sPh[i] = 2; sOff[sp] = sOff[i] + n2; sN[sp] = n - n2; sPh[sp] = 0; ++sp; }
        else {
            int bI = --vp; int aI = --vp;      // a = left child, b = right child
            int lev = (vLev[aI] > vLev[bI] ? vLev[aI] : vLev[bI]) + 1;
            oA[nops] = vSlot[aI]; oB[nops] = vSlot[bI]; oD[nops] = NLCAP + nops; oL[nops] = lev;
            vSlot[vp] = NLCAP + nops; vLev[vp] = lev; ++vp; ++nops; --sp;
        }
    }
    s.nl = nl; s.nops = nops; s.root = vSlot[0];
    int maxl = 0;
    for (int k = 0; k < nops; ++k) if (oL[k] > maxl) maxl = oL[k];
    s.nlev = maxl;
    int cnt[36] = {};
    for (int k = 0; k < nops; ++k) cnt[oL[k]]++;
    int run = 0;
    s.lvlStart[0] = 0;
    for (int k = 1; k <= maxl; ++k) { s.lvlStart[k] = run; run += cnt[k]; cnt[k] = s.lvlStart[k]; }
    s.lvlStart[maxl + 1] = run;
    for (int k = 0; k < nops; ++k) { int p = cnt[oL[k]]++; s.sA[p] = oA[k]; s.sB[p] = oB[k]; s.sD[p] = oD[k]; }
    return s;
}

constexpr SchedT SCHL = build_sched(0, NSPLIT);
constexpr SchedT SCHR = build_sched(NSPLIT, V - NSPLIT);
static_assert(SCHL.nl <= NLCAP && SCHR.nl <= NLCAP, "leaf overflow");
static_assert(SCHL.nops <= NLCAP && SCHR.nops <= NLCAP, "op overflow");
static_assert(SCHL.nlev <= 34 && SCHR.nlev <= 34, "level overflow");
static_assert(SCHL.minLeaf >= 8 && SCHR.minLeaf >= 8, "leaf < 8 breaks 8-lane cluster");

// -------- init --------
__global__ void k_init(const int* __restrict__ initial_ids, const float* __restrict__ state,
                       float* __restrict__ cache, int* __restrict__ ids, float* __restrict__ scores) {
    int b = blockIdx.x, t = threadIdx.x;
    cache[b * D + t] = state[b * D + t];
    if (t == 0) { ids[b * MAXLEN] = initial_ids[b]; scores[b] = 0.f; }
}

// -------- x = tanh(seqdot(cache,U) + emb[last]); writes x AND xT --------
__global__ __launch_bounds__(256) void k_embed(const float* __restrict__ cache, const int* __restrict__ ids,
                                               const float* __restrict__ emb, const float* __restrict__ U,
                                               float* __restrict__ x, float* __restrict__ xT, int step) {
    int rr = blockIdx.x, j = threadIdx.x;
    __shared__ float sc[D];
    sc[j] = cache[rr * D + j];
    __syncthreads();
    int last = ids[rr * MAXLEN + step];
    float acc = 0.f;
    for (int d = 0; d < D; ++d)
        acc = __fadd_rn(acc, __fmul_rn(sc[d], U[d * D + j]));   // sequential f32, no FMA
    float pre = __fadd_rn(acc, emb[(size_t)last * D + j]);
    float xv = (float)tanh((double)pre);
    x[rr * D + j] = xv;
    xT[(size_t)j * 256 + rr] = xv;                              // fused transpose write
}

// -------- logits GEMM (scalar, 16 rows/block, XCD-swizzled) + segment max --------
__global__ __launch_bounds__(256) void k_gemm(const float* __restrict__ xT, const float* __restrict__ W,
                                              float* __restrict__ L, float* __restrict__ segMax,
                                              int rows, int rowBlocks) {
    int t = threadIdx.x;
    int xcd = blockIdx.x % NXCD;
    int slot = blockIdx.x / NXCD;
    int vidx = slot / rowBlocks;
    int rg = slot % rowBlocks;
    int vseg = xcd + NXCD * vidx;
    if (vseg >= NSEG) return;
    int v = vseg * 256 + t;
    int r0 = rg * GROWS;
    bool vok = (v < V);
    float acc[GROWS];
#pragma unroll
    for (int r = 0; r < GROWS; ++r) acc[r] = 0.f;
    for (int d = 0; d < D; ++d) {
        float w = vok ? W[(size_t)d * V + v] : 0.f;  // coalesced vector load
        const float* xp = xT + (size_t)d * 256 + r0; // block-uniform -> s_load
#pragma unroll
        for (int r = 0; r < GROWS; ++r)
            acc[r] = __fadd_rn(acc[r], __fmul_rn(xp[r], w));   // same per-(r,v) order as R10-R27
    }
#pragma unroll
    for (int r = 0; r < GROWS; ++r)
        if (vok && r0 + r < rows) L[(size_t)(r0 + r) * VP + v] = acc[r];

    // segment max per row (fmax reduce: order-independent, exact)
    __shared__ float wmax[4][GROWS];
    int wave = t >> 6, lane = t & 63;
#pragma unroll
    for (int r = 0; r < GROWS; ++r) {
        float mv = vok ? acc[r] : FNEG_INF;
#pragma unroll
        for (int o = 1; o < 64; o <<= 1) mv = fmaxf(mv, __shfl_xor(mv, o));
        if (lane == 0) wmax[wave][r] = mv;
    }
    __syncthreads();
    if (t < GROWS && r0 + t < rows) {
        float mv = fmaxf(fmaxf(wmax[0][t], wmax[1][t]), fmaxf(wmax[2][t], wmax[3][t]));
        segMax[(size_t)(r0 + t) * NSEG + vseg] = mv;
    }
}

// -------- exact numpy-pairwise base-case element: f32(exp(f64(L-m))) --------
__device__ __forceinline__ float Ev(const float* __restrict__ a, float m, int i) {
    return (float)exp((double)__fsub_rn(a[i], m));
}

// -------- half-tree exp-sum: blockIdx.y = 0 (left) / 1 (right) --------
__global__ __launch_bounds__(1024) void k_lsf(const float* __restrict__ L, const float* __restrict__ segMax,
                                              float* __restrict__ pSum) {
    int rr = blockIdx.x, half = blockIdx.y, t = threadIdx.x;
    const float* Lr = L + (size_t)rr * VP;
    __shared__ float mS;
    __shared__ float vals[SLOTCAP];

    if (t < 64) {
        float mv = FNEG_INF;
        for (int s = t; s < NSEG; s += 64) mv = fmaxf(mv, segMax[(size_t)rr * NSEG + s]);
#pragma unroll
        for (int o = 1; o < 64; o <<= 1) mv = fmaxf(mv, __shfl_xor(mv, o));
        if (t == 0) mS = mv;
    }
    __syncthreads();
    float m = mS;

    const int* leafOff = half ? SCHR.leafOff : SCHL.leafOff;
    const int* leafN   = half ? SCHR.leafN   : SCHL.leafN;
    const int* sA      = half ? SCHR.sA      : SCHL.sA;
    const int* sB      = half ? SCHR.sB      : SCHL.sB;
    const int* sD      = half ? SCHR.sD      : SCHL.sD;
    const int* lvlStart= half ? SCHR.lvlStart: SCHL.lvlStart;
    int nl   = half ? SCHR.nl   : SCHL.nl;
    int nlev = half ? SCHR.nlev : SCHL.nlev;
    int root = half ? SCHR.root : SCHL.root;

    // leaf sums: 8-lane clusters, numpy accumulator j = lane
    int cl = t >> 3, j = t & 7;
    for (int l = cl; l < nl; l += 128) {
        int off = leafOff[l], n = leafN[l];
        int n8 = n - (n % 8);
        float r = Ev(Lr, m, off + j);
        for (int i = 8; i < n8; i += 8) r = __fadd_rn(r, Ev(Lr, m, off + i + j));
        float s1 = __fadd_rn(r,  __shfl_xor(r, 1));     // commutative: bitwise == numpy tree
        float s2 = __fadd_rn(s1, __shfl_xor(s1, 2));
        float s3 = __fadd_rn(s2, __shfl_xor(s2, 4));
        if (j == 0) {
            float res = s3;
            for (int i = n8; i < n; ++i) res = __fadd_rn(res, Ev(Lr, m, off + i));
            vals[l] = res;
        }
    }
    __syncthreads();
    for (int lev = 1; lev <= nlev; ++lev) {
        for (int i = lvlStart[lev] + t; i < lvlStart[lev + 1]; i += 1024)
            vals[sD[i]] = __fadd_rn(vals[sA[i]], vals[sB[i]]);
        __syncthreads();
    }
    if (t == 0) pSum[rr * 2 + half] = vals[root];
}

// -------- k_top: m + lsf finalize + LDS-chunk group top-2 + extraction --------
__global__ __launch_bounds__(1024) void k_top(const float* __restrict__ L, const float* __restrict__ segMax,
                                              const float* __restrict__ pSum, const float* __restrict__ scores,
                                              float* __restrict__ candV, int* __restrict__ candI) {
    int rr = blockIdx.x, t = threadIdx.x;
    const float* Lr = L + (size_t)rr * VP;
    __shared__ float mS;
    __shared__ float buf[CHUNK];
    __shared__ float gval[NG]; __shared__ int gidx[NG]; __shared__ unsigned gmask[NG];
    __shared__ float gv2[NG]; __shared__ int gi2[NG];
    __shared__ float sgval[64]; __shared__ int sgtok[64]; __shared__ int sggrp[64];

    if (t < 64) {
        float mv = FNEG_INF;
        for (int s = t; s < NSEG; s += 64) mv = fmaxf(mv, segMax[(size_t)rr * NSEG + s]);
#pragma unroll
        for (int o = 1; o < 64; o <<= 1) mv = fmaxf(mv, __shfl_xor(mv, o));
        if (t == 0) mS = mv;
    }
    __syncthreads();
    float m = mS;
    float lsf = (float)log((double)__fadd_rn(pSum[rr * 2 + 0], pSum[rr * 2 + 1]));  // root combine
    float sc = scores[rr];

    // ---- group top-2 via LDS chunks, rotated per-thread scan (no shuffles) ----
    for (int c = 0; c < (V + CHUNK - 1) / CHUNK; ++c) {
        int base = c * CHUNK;
        int cnt = V - base; if (cnt > CHUNK) cnt = CHUNK;
        int cnt4 = (cnt + 3) >> 2;                       // pad reads stay < VP
        const float4* L4 = (const float4*)(Lr + base);
        float4* B4 = (float4*)buf;
        for (int i = t; i < cnt4; i += 1024) B4[i] = L4[i];
        __syncthreads();
        int gBase = base >> 5;
        int gCnt = (cnt + 31) >> 5;
        for (int g = gBase + t; g < gBase + gCnt; g += 1024) {
            int local = (g - gBase) * 32;
            float b1v = FNEG_INF, b2v = FNEG_INF; int b1i = 0x7fffffff, b2i = 0x7fffffff;
            for (int k = 0; k < 32; ++k) {
                int kk = (k + t) & 31;                   // rotation: conflict-free
                int col = g * 32 + kk;
                if (col >= V) continue;
                float val = __fadd_rn(sc, __fsub_rn(__fsub_rn(buf[local + kk], m), lsf));
                if (val > b1v || (val == b1v && col < b1i)) {
                    b2v = b1v; b2i = b1i; b1v = val; b1i = col;
                } else if (val > b2v || (val == b2v && col < b2i)) {
                    b2v = val; b2i = col;
                }
            }
            gval[g] = b1v; gidx[g] = b1i; gv2[g] = b2v; gi2[g] = b2i; gmask[g] = 0u;
        }
        __syncthreads();
    }

    // ---- supergroup table ----
    int wv = t >> 6, ln = t & 63;
    for (int s2 = wv * 2; s2 < NSG; s2 += 32) {
        int s = s2 + (ln >> 5);
        int g = s2 * 32 + ln;
        bool lives = (s < NSG);
        bool live = lives && (g < NG);
        float val = live ? gval[g] : FNEG_INF;
        int tok = live ? gidx[g] : 0x7fffffff;
        int grp = live ? g : -1;
#pragma unroll
        for (int o = 1; o < 32; o <<= 1) {
            float v2 = __shfl_xor(val, o);
            int t2 = __shfl_xor(tok, o);
            int g3 = __shfl_xor(grp, o);
            if (v2 > val || (v2 == val && t2 < tok)) { val = v2; tok = t2; grp = g3; }
        }
        if (lives && (ln & 31) == 0) { sgval[s] = val; sgtok[s] = tok; sggrp[s] = grp; }
    }
    __syncthreads();
    if (t >= 64) return;                                  // rounds run on wave 0 only

    // ---- 32 extraction rounds (pure LDS; global rescan only on repeat hits) ----
    for (int it = 0; it < 32; ++it) {
        float val = (t < NSG) ? sgval[t] : FNEG_INF;
        int tok = (t < NSG) ? sgtok[t] : 0x7fffffff;
        int grp = (t < NSG) ? sggrp[t] : -1;
#pragma unroll
        for (int o = 1; o < 64; o <<= 1) {                // butterfly all-reduce
            float v2 = __shfl_xor(val, o);
            int t2 = __shfl_xor(tok, o);
            int g3 = __shfl_xor(grp, o);
            if (v2 > val || (v2 == val && t2 < tok)) { val = v2; tok = t2; grp = g3; }
        }
        int gw = grp, tw = tok;                           // all lanes hold winner
        unsigned oldmask = gmask[gw];                     // read before write (program order)
        unsigned newmask = oldmask | (1u << (tw & 31));
        if (t == 0) {
            candV[rr * 32 + it] = val;
            candI[rr * 32 + it] = tw;
            gmask[gw] = newmask;
        }
        if (__popc(oldmask) == 0) {                       // first hit: promote stored 2nd
            if (t == 0) { gval[gw] = gv2[gw]; gidx[gw] = gi2[gw]; }
        } else {                                          // repeat hit: masked global rescan
            int col = gw * 32 + (t & 31);
            bool live = (col < V) && !((newmask >> (t & 31)) & 1u);
            float nv = live ? __fadd_rn(sc, __fsub_rn(__fsub_rn(Lr[col], m), lsf)) : FNEG_INF;
            int nix = live ? col : 0x7fffffff;
#pragma unroll
            for (int o = 1; o < 32; o <<= 1) {
                float v2 = __shfl_xor(nv, o);
                int i2 = __shfl_xor(nix, o);
                if (v2 > nv || (v2 == nv && i2 < nix)) { nv = v2; nix = i2; }
            }
            if (t == 0) { gval[gw] = nv; gidx[gw] = nix; }
        }
        // rebuild supergroup of gw
        int s = gw >> 5;
        int gg = s * 32 + (t & 31);
        bool lv = (gg < NG);
        float sv = lv ? gval[gg] : FNEG_INF;
        int st = lv ? gidx[gg] : 0x7fffffff;
        int sg2 = lv ? gg : -1;
#pragma unroll
        for (int o = 1; o < 32; o <<= 1) {
            float v2 = __shfl_xor(sv, o);
            int t2 = __shfl_xor(st, o);
            int g3 = __shfl_xor(sg2, o);
            if (v2 > sv || (v2 == sv && t2 < st)) { sv = v2; st = t2; sg2 = g3; }
        }
        if (t == 0) { sgval[s] = sv; sgtok[s] = st; sggrp[s] = sg2; }
    }
}

// -------- PARALLEL per-batch merge (unchanged from R15) --------
__global__ __launch_bounds__(256) void k_merge(const float* __restrict__ candV, const int* __restrict__ candI,
                                               float* __restrict__ scoresNxt,
                                               const int* __restrict__ idsCur, int* __restrict__ idsNxt,
                                               const float* __restrict__ x, float* __restrict__ cacheNxt,
                                               int beam0, int step) {
    int b = blockIdx.x, t = threadIdx.x;
    int n = beam0 * BEAM;
    __shared__ float mval[BEAM * BEAM]; __shared__ int mbeam[BEAM * BEAM]; __shared__ int mtok[BEAM * BEAM];
    __shared__ float rv[256]; __shared__ int rk[256]; __shared__ int rs[256];
    __shared__ float wval[BEAM]; __shared__ int wbeam[BEAM]; __shared__ int wtok[BEAM];

    for (int i = t; i < n; i += 256) {
        int beam = i >> 5;
        int rr = b * beam0 + beam;
        mval[i] = candV[rr * BEAM + (i & 31)];
        mbeam[i] = beam;
        mtok[i] = candI[rr * BEAM + (i & 31)];
    }
    __syncthreads();

    for (int it = 0; it < BEAM; ++it) {
        float bv = FNEG_INF; int bk = 0x7fffffff; int bs = -1;
        for (int i = t; i < n; i += 256) {
            float v = mval[i];
            int gi = mbeam[i] * V + mtok[i];
            if (v > bv || (v == bv && gi < bk)) { bv = v; bk = gi; bs = i; }
        }
        rv[t] = bv; rk[t] = bk; rs[t] = bs; __syncthreads();
        for (int o = 128; o > 0; o >>= 1) {
            if (t < o) {
                if (rv[t + o] > rv[t] || (rv[t + o] == rv[t] && rk[t + o] < rk[t])) {
                    rv[t] = rv[t + o]; rk[t] = rk[t + o]; rs[t] = rs[t + o];
                }
            }
            __syncthreads();
        }
        if (t == 0) {
            int w = rs[0];
            wval[it] = rv[0]; wbeam[it] = mbeam[w]; wtok[it] = mtok[w];
            mval[w] = FNEG_INF;                      // consume winner
        }
        __syncthreads();
    }

    if (t < BEAM) {
        scoresNxt[b * BEAM + t] = wval[t];
        int src = b * beam0 + wbeam[t];
        for (int u = 0; u <= step; ++u)
            idsNxt[(b * BEAM + t) * MAXLEN + u] = idsCur[src * MAXLEN + u];
        idsNxt[(b * BEAM + t) * MAXLEN + step + 1] = wtok[t];
    }
    __syncthreads();
    for (int j = 0; j < BEAM; ++j) {
        int src = b * beam0 + wbeam[j];
        cacheNxt[(size_t)(b * BEAM + j) * D + t] = x[(size_t)src * D + t];
    }
}

// -------- output as float32 --------
__global__ void k_out(const int* __restrict__ ids, const float* __restrict__ scores, float* __restrict__ out) {
    int t = blockIdx.x * 256 + threadIdx.x;
    const int NI = B * BEAM * MAXLEN;
    if (t < NI) out[t] = (float)ids[t];
    else if (t < NI + B * BEAM) out[t] = scores[t - NI];
}

extern "C" void kernel_launch(void* const* d_in, const int* in_sizes, int n_in,
                              void* d_out, int out_size, void* d_ws, size_t ws_size,
                              hipStream_t stream) {
    const int* initial_ids = (const int*)d_in[0];
    const float* state = (const float*)d_in[1];
    const float* emb = (const float*)d_in[2];
    const float* W = (const float*)d_in[3];
    const float* U = (const float*)d_in[4];

    char* ws = (char*)d_ws;
    size_t off = 0;
    float* L = (float*)(ws + off);       off += (size_t)256 * VP * 4;
    float* x = (float*)(ws + off);       off += 256 * D * 4;
    float* xT = (float*)(ws + off);      off += 256 * D * 4;
    float* cacheA = (float*)(ws + off);  off += 256 * D * 4;
    float* cacheB = (float*)(ws + off);  off += 256 * D * 4;
    float* scoresA = (float*)(ws + off); off += 256 * 4;
    float* scoresB = (float*)(ws + off); off += 256 * 4;
    int* idsA = (int*)(ws + off);        off += 256 * MAXLEN * 4;
    int* idsB = (int*)(ws + off);        off += 256 * MAXLEN * 4;
    float* candV = (float*)(ws + off);   off += 256 * 32 * 4;
    int* candI = (int*)(ws + off);       off += 256 * 32 * 4;
    float* segMax = (float*)(ws + off);  off += (size_t)256 * NSEG * 4;
    float* pSum = (float*)(ws + off);    off += 256 * 2 * 4;

    if (ws_size < off) return;

    k_init<<<B, 256, 0, stream>>>(initial_ids, state, cacheA, idsA, scoresA);

    float* cCur = cacheA; float* cNxt = cacheB;
    float* sCur = scoresA; float* sNxt = scoresB;
    int* iCur = idsA; int* iNxt = idsB;

    for (int step = 0; step < STEPS; ++step) {
        int beam0 = (step == 0) ? 1 : BEAM;
        int rows = B * beam0;

        k_embed<<<rows, 256, 0, stream>>>(cCur, iCur, emb, U, x, xT, step);

        int rowBlocks = (rows + GROWS - 1) / GROWS;
        k_gemm<<<VSEGP * rowBlocks, 256, 0, stream>>>(xT, W, L, segMax, rows, rowBlocks);

        dim3 gl(rows, 2);
        k_lsf<<<gl, 1024, 0, stream>>>(L, segMax, pSum);
        k_top<<<rows, 1024, 0, stream>>>(L, segMax, pSum, sCur, candV, candI);
        k_merge<<<B, 256, 0, stream>>>(candV, candI, sNxt, iCur, iNxt, x, cNxt, beam0, step);

        float* tf; int* ti;
        tf = cCur; cCur = cNxt; cNxt = tf;
        tf = sCur; sCur = sNxt; sNxt = tf;
        ti = iCur; iCur = iNxt; iNxt = ti;
    }

    k_out<<<(B * BEAM * MAXLEN + B * BEAM + 255) / 256, 256, 0, stream>>>(iCur, sCur, (float*)d_out);
}